// Round 24
// baseline (121.786 us; speedup 1.0000x reference)
//
#include <hip/hip_runtime.h>
#include <hip/hip_bf16.h>
#include <math.h>

// Problem constants
#define T_ 4
#define N_ 16
#define F_ 6
#define L_ 1024
#define A_ 21
#define K_ 20
#define U_ 256
#define LOUT 1005            // L - K + 1
#define NIMG 384             // T*N*F
#define SZ_S (T_*N_*U_)      // 16384
#define SZ_R (K_*A_*U_)      // 107520

// Packed-X geometry: row stride 24 shorts (48 B). For output row l, contraction
// slot c maps to tap=c/24, col=c%24 (independent of l). Valid slots 0..476 ->
// 15 K-steps of 32 (480); cols 21..23 zero in R.
#define XPR 24               // shorts per packed row
#define XROWS 1056           // padded rows per image
#define NSTEP 15             // K-steps of 32 slots
#define XWCH 7               // private X chunks of 1 KB per wave (149 rows)

typedef __attribute__((ext_vector_type(8))) short short8;   // 8 bf16 (4 VGPR)
typedef __attribute__((ext_vector_type(4))) float f32x4;    // 4 f32 acc
typedef __attribute__((ext_vector_type(4))) unsigned int uint4v;

__device__ __forceinline__ unsigned short f2bf(float f) {
  unsigned int u = __float_as_uint(f);
  u += 0x7FFFu + ((u >> 16) & 1u);   // round to nearest even
  return (unsigned short)(u >> 16);
}

__device__ __forceinline__ void atomicMaxF(float* addr, float val) {
  if (val >= 0.f) atomicMax((int*)addr, __float_as_int(val));
  else            atomicMin((unsigned int*)addr, __float_as_uint(val));
}

// Async global->LDS, 16B per lane. LDS dest is wave-uniform base + lane*16.
__device__ __forceinline__ void gload_lds16(const void* g, void* l) {
  __builtin_amdgcn_global_load_lds(
      (const __attribute__((address_space(1))) void*)g,
      (__attribute__((address_space(3))) void*)l, 16, 0, 0);
}

// Merged pre-pass (single launch): S init, R (fp32 exact) -> d_out,
// Rt = bf16 R in slot order with the G21 both-sides XOR swizzle (R23):
// within each 64 B u-row, 16 B slot-group s4 stored at s4 ^ ((u>>1)&3).
// X fp32 -> packed bf16 Xp unchanged.
__global__ void xprep_kernel(const float* __restrict__ X,
                             const float* __restrict__ P_logit,
                             const float* __restrict__ Q,
                             float* __restrict__ out,
                             unsigned short* __restrict__ Rt,
                             unsigned int* __restrict__ Xp32) {
  int t = blockIdx.x * blockDim.x + threadIdx.x;
  if (t < SZ_S) out[t] = -INFINITY;            // S init for atomic max

  if (t < K_ * U_) {                           // R / Rt part
    int k = t / U_;
    int u = t - k * U_;
    const float* pl = P_logit + (size_t)k * A_ * U_ + u;
    float v[A_];
    float m = -INFINITY;
#pragma unroll
    for (int a = 0; a < A_; ++a) { v[a] = pl[(size_t)a * U_]; m = fmaxf(m, v[a]); }
    float s = 0.f;
#pragma unroll
    for (int a = 0; a < A_; ++a) { v[a] = expf(v[a] - m); s += v[a]; }
    float qs = 0.f;
#pragma unroll
    for (int a = 0; a < A_; ++a) qs += Q[a];
    float eps = qs * (1.0f / A_);
    float invs = 1.f / s;
    float* Rout = out + SZ_S;
    const int um = (u >> 1) & 3;               // swizzle mask for this u-row
#pragma unroll
    for (int a = 0; a < XPR; ++a) {
      unsigned short bv = 0;
      if (a < A_) {
        float r = logf(fmaxf(v[a] * invs / Q[a], eps));
        Rout[(size_t)(k * A_ + a) * U_ + u] = r;
        bv = f2bf(r);
      }
      int sl = k * XPR + a;
      int w = sl & 31;                         // slot within 32-slot step row
      int widx = (((w >> 3) ^ um) << 3) | (w & 7);   // swizzled position
      Rt[(size_t)(sl >> 5) * (U_ * 32) + u * 32 + widx] = bv;
    }
  }

  if (t < NIMG * XROWS * 12) {                 // X conversion part
    int w  = t % 12;
    int rl = t / 12;               // n*XROWS + row
    int row = rl % XROWS;
    int n   = rl / XROWS;
    int c0 = w * 2;
    float v0 = 0.f, v1 = 0.f;
    if (row < L_) {
      const float* xr = X + ((size_t)n * L_ + row) * A_;
      if (c0 < A_)     v0 = xr[c0];
      if (c0 + 1 < A_) v1 = xr[c0 + 1];
    }
    unsigned int o = (unsigned int)f2bf(v0) | ((unsigned int)f2bf(v1) << 16);
    Xp32[(size_t)rl * 12 + w] = o;
  }
}

// Conv as one GEMM: M=u (A=R slots), N=l (B=packed-X window), K=480 (15 steps).
// R24 = R23 per-wave schedule (persistent R, wave-private X, double acc,
// paced stores {1,2,4,5,7,9,10,12}, T14 reg-staged X, zero barriers after
// prologue) at HALVED block granularity: block = 64u x 1024l, 2 waves (128
// threads), wave tile unchanged 64u x 128l. LDS = 60 KB R + 14 KB X = 74 KB
// -> TWO blocks co-resident per CU, so one block's boundary (prologue + cold
// tile + tail drain, ~25-30K cyc) hides under the other's steady-state
// compute+stores. Total R-stage traffic unchanged (1536 x 60 KB = 92 MB).
// u0 is 64-aligned (bits 1-2 zero) so the R23 swizzle identity holds.
__global__ __launch_bounds__(128, 1) void conv_kernel(
    const unsigned short* __restrict__ Xp,
    const unsigned short* __restrict__ Rt,
    float* __restrict__ out) {
  __shared__ __align__(16) unsigned short lds_r[NSTEP * 2048];     // 60 KB
  __shared__ __align__(16) unsigned short lds_xp[2][XWCH * 512];   // 14 KB

  const int n  = blockIdx.z;
  const int u0 = blockIdx.x * 64;      // 4 u-tiles of 64
  const int wid  = threadIdx.x >> 6;   // 0..1 = wave l position, 128 l each
  const int lane = threadIdx.x & 63;

  // wave's private X source: rows t*256 + wid*128 .. +148 (halo 19 incl.)
  const char* xsrc = (const char*)Xp +
      ((size_t)n * XROWS + wid * 128) * (XPR * 2);
  const char* rsrc = (const char*)Rt + (size_t)u0 * 64;   // block's 64-u range
  char* xdst = (char*)&lds_xp[wid][0];

  // ---- prologue: ALL of R (60 x 1KB chunks, 30/wave) + private X tile 0
  // per step: 4 KB contiguous (rows u0..u0+63); chunk c -> step c>>2, qtr c&3
  for (int c = wid; c < NSTEP * 4; c += 2)
    gload_lds16(rsrc + (size_t)(c >> 2) * (U_ * 64) + (c & 3) * 1024 + lane * 16,
                (char*)lds_r + c * 1024);
#pragma unroll
  for (int c = 0; c < XWCH; ++c)
    gload_lds16(xsrc + c * 1024 + lane * 16, xdst + c * 1024);
  asm volatile("s_waitcnt vmcnt(0)" ::: "memory");
  __builtin_amdgcn_s_barrier();        // the ONLY barrier: lds_r visibility

  const int fl = lane & 15;            // frag row (A: u) / col (B: l)
  const int fj = lane >> 4;            // k sub-chunk (8 shorts each)
  // R read offset with baked-in swizzle (u0, ut*16 have bits 1-2 zero):
  const int rfo = fl * 32 + ((fj ^ ((fl >> 1) & 3)) << 3);
  const unsigned short* xb =
      (const unsigned short*)xdst + fl * XPR + (fj << 3);
  const int ug = fj << 2;

  float* Z = out + SZ_S + SZ_R;
  float pmax[4][4];                    // [ut][reg], carried across all tiles
#pragma unroll
  for (int ut = 0; ut < 4; ++ut)
#pragma unroll
    for (int r = 0; r < 4; ++r) pmax[ut][r] = -INFINITY;

  f32x4 accA[4][8], accB[4][8];        // double accumulators (256 VGPR)
  uint4v xr[XWCH];                     // X reg-stage for next tile (28 VGPR)

  // paced store-group schedule: group g at step sgk[g]
#define SGK(k) ((k)==1?0:(k)==2?1:(k)==4?2:(k)==5?3:(k)==7?4:(k)==9?5:   \
                (k)==10?6:(k)==12?7:-1)

#define ZERO(ACC)                                                            \
  {                                                                          \
    _Pragma("unroll")                                                        \
    for (int ut = 0; ut < 4; ++ut)                                           \
      _Pragma("unroll")                                                      \
      for (int lt = 0; lt < 8; ++lt)                                         \
        (ACC)[ut][lt] = (f32x4){0.f, 0.f, 0.f, 0.f};                         \
  }

  // R frag(k, ut): lds_r + k*2048 + (ut*16)*32 + rfo   (shorts)
#define KSTEP(K, ACC)                                                        \
  {                                                                          \
    short8 xfr[8], rfr[4];                                                   \
    const unsigned short* rb = lds_r + (K) * 2048 + rfo;                     \
    _Pragma("unroll")                                                        \
    for (int lt = 0; lt < 8; ++lt)                                           \
      xfr[lt] = *(const short8*)(xb + lt * (16 * XPR) + (K) * 32);           \
    _Pragma("unroll")                                                        \
    for (int ut = 0; ut < 4; ++ut)                                           \
      rfr[ut] = *(const short8*)(rb + ut * (16 * 32));                       \
    _Pragma("unroll")                                                        \
    for (int ut = 0; ut < 4; ++ut)                                           \
      _Pragma("unroll")                                                      \
      for (int lt = 0; lt < 8; ++lt)                                         \
        (ACC)[ut][lt] = __builtin_amdgcn_mfma_f32_16x16x32_bf16(             \
            rfr[ut], xfr[lt], (ACC)[ut][lt], 0, 0, 0);                       \
  }

  // store lt-group LT of tile TT from ACC (tiles 0..2: always in-bounds)
#define STORE4(ACC, TT, LT)                                                  \
  {                                                                          \
    const int l = (TT) * 256 + wid * 128 + (LT) * 16 + fl;                   \
    float* zrow = Z + ((size_t)n * LOUT + l) * U_ + u0 + ug;                 \
    _Pragma("unroll")                                                        \
    for (int ut = 0; ut < 4; ++ut) {                                         \
      f32x4 v = (ACC)[ut][LT];                                               \
      *(f32x4*)(zrow + ut * 16) = v;                                         \
      _Pragma("unroll")                                                      \
      for (int r = 0; r < 4; ++r) pmax[ut][r] = fmaxf(pmax[ut][r], v[r]);    \
    }                                                                        \
  }

#define XLOADS(T1)                                                           \
  {                                                                          \
    const char* xs = xsrc + (size_t)(T1) * (256 * XPR * 2);                  \
    _Pragma("unroll")                                                        \
    for (int c = 0; c < XWCH; ++c)                                           \
      xr[c] = *(const uint4v*)(xs + c * 1024 + lane * 16);                   \
  }

#define XWRITE()                                                             \
  {                                                                          \
    _Pragma("unroll")                                                        \
    for (int c = 0; c < XWCH; ++c)                                           \
      *(uint4v*)(xdst + c * 1024 + lane * 16) = xr[c];                       \
  }

  // ---- tile 0: compute accA; reg-load X1 (issued before any stores)
  ZERO(accA)
  XLOADS(1)
#pragma unroll
  for (int k = 0; k < NSTEP; ++k) KSTEP(k, accA)
  asm volatile("s_waitcnt vmcnt(0)" ::: "memory");   // xr ready (only loads)
  XWRITE()

  // ---- tile 1: compute accB; paced stores of tile 0; reg-load X2
  ZERO(accB)
  XLOADS(2)
#pragma unroll
  for (int k = 0; k < NSTEP; ++k) {
    KSTEP(k, accB)
    if (SGK(k) >= 0) STORE4(accA, 0, SGK(k))
  }
  asm volatile("s_waitcnt vmcnt(32)" ::: "memory");  // retire 7 oldest = xloads
  XWRITE()

  // ---- tile 2: compute accA; paced stores of tile 1; reg-load X3
  ZERO(accA)
  XLOADS(3)
#pragma unroll
  for (int k = 0; k < NSTEP; ++k) {
    KSTEP(k, accA)
    if (SGK(k) >= 0) STORE4(accB, 1, SGK(k))
  }
  asm volatile("s_waitcnt vmcnt(32)" ::: "memory");
  XWRITE()

  // ---- tile 3: compute accB; paced stores of tile 2
  ZERO(accB)
#pragma unroll
  for (int k = 0; k < NSTEP; ++k) {
    KSTEP(k, accB)
    if (SGK(k) >= 0) STORE4(accA, 2, SGK(k))
  }

  // ---- tail: store tile 3 (guarded: rows 768..1023 vs LOUT=1005)
#pragma unroll
  for (int lt = 0; lt < 8; ++lt) {
    const int l = 768 + wid * 128 + lt * 16 + fl;
    if (l < LOUT) {
      float* zrow = Z + ((size_t)n * LOUT + l) * U_ + u0 + ug;
#pragma unroll
      for (int ut = 0; ut < 4; ++ut) {
        f32x4 v = accB[ut][lt];
        *(f32x4*)(zrow + ut * 16) = v;
#pragma unroll
        for (int r = 0; r < 4; ++r) pmax[ut][r] = fmaxf(pmax[ut][r], v[r]);
      }
    }
  }

#undef SGK
#undef ZERO
#undef KSTEP
#undef STORE4
#undef XLOADS
#undef XWRITE

  // ---- S epilogue: reduce over the frag's 16 cols (fl), atomics once.
#pragma unroll
  for (int off = 1; off < 16; off <<= 1)
#pragma unroll
    for (int ut = 0; ut < 4; ++ut)
#pragma unroll
      for (int r = 0; r < 4; ++r)
        pmax[ut][r] = fmaxf(pmax[ut][r], __shfl_xor(pmax[ut][r], off));

  if (fl == 0) {                       // lanes fj*16
    const int tn = n / F_;
    float* Sp = out + (size_t)tn * U_ + u0 + ug;
#pragma unroll
    for (int ut = 0; ut < 4; ++ut)
#pragma unroll
      for (int r = 0; r < 4; ++r)
        atomicMaxF(Sp + ut * 16 + r, pmax[ut][r]);
  }
}

extern "C" void kernel_launch(void* const* d_in, const int* in_sizes, int n_in,
                              void* d_out, int out_size, void* d_ws, size_t ws_size,
                              hipStream_t stream) {
  const float* X       = (const float*)d_in[0];
  const float* P_logit = (const float*)d_in[1];
  const float* Q       = (const float*)d_in[2];
  float* out = (float*)d_out;

  unsigned short* Rt = (unsigned short*)d_ws;            // 240 KB
  unsigned short* Xp = (unsigned short*)((char*)d_ws + 262144);
  // Xp: NIMG*XROWS*24 shorts (~18.6 MB). All staged rows <= 1044 < 1056:
  // fully in-bounds; no over-read.

  int xthreads = NIMG * XROWS * 12;
  hipLaunchKernelGGL(xprep_kernel, dim3((xthreads + 255) / 256), dim3(256),
                     0, stream, X, P_logit, Q, out, Rt, (unsigned int*)Xp);
  dim3 grid(4, 1, NIMG);   // 64-u tiles x images; 4 l-tiles looped in-kernel
  hipLaunchKernelGGL(conv_kernel, grid, dim3(128), 0, stream, Xp, Rt, out);
}

// Round 25
// 120.123 us; speedup vs baseline: 1.0138x; 1.0138x over previous
//
#include <hip/hip_runtime.h>
#include <hip/hip_bf16.h>
#include <math.h>

// Problem constants
#define T_ 4
#define N_ 16
#define F_ 6
#define L_ 1024
#define A_ 21
#define K_ 20
#define U_ 256
#define LOUT 1005            // L - K + 1
#define NIMG 384             // T*N*F
#define SZ_S (T_*N_*U_)      // 16384
#define SZ_R (K_*A_*U_)      // 107520

// Packed-X geometry: row stride 24 shorts (48 B). For output row l, contraction
// slot c maps to tap=c/24, col=c%24 (independent of l). Valid slots 0..476 ->
// 15 K-steps of 32 (480); cols 21..23 zero in R (so X pad cols may be garbage).
#define XPR 24               // shorts per packed row
#define NSTEP 15             // K-steps of 32 slots
#define XWCH 7               // private X chunks of 1 KB per wave (149 rows)
#define XF_MAX ((size_t)NIMG * L_ * A_ - 8)   // clamp so 32-B reads stay in-bounds

typedef __attribute__((ext_vector_type(8))) short short8;   // 8 bf16 (4 VGPR)
typedef __attribute__((ext_vector_type(4))) float f32x4;    // 4 f32 acc
typedef __attribute__((ext_vector_type(4))) unsigned int uint4v;

__device__ __forceinline__ unsigned short f2bf(float f) {
  unsigned int u = __float_as_uint(f);
  u += 0x7FFFu + ((u >> 16) & 1u);   // round to nearest even
  return (unsigned short)(u >> 16);
}

__device__ __forceinline__ void atomicMaxF(float* addr, float val) {
  if (val >= 0.f) atomicMax((int*)addr, __float_as_int(val));
  else            atomicMin((unsigned int*)addr, __float_as_uint(val));
}

// Async global->LDS, 16B per lane. LDS dest is wave-uniform base + lane*16.
__device__ __forceinline__ void gload_lds16(const void* g, void* l) {
  __builtin_amdgcn_global_load_lds(
      (const __attribute__((address_space(1))) void*)g,
      (__attribute__((address_space(3))) void*)l, 16, 0, 0);
}

// Small pre-pass (16K threads): S init, R (fp32 exact) -> d_out, Rt = bf16 R
// in slot order with the G21 both-sides XOR swizzle (R23): within each 64 B
// u-row, 16 B slot-group s4 stored at s4 ^ ((u>>1)&3). NO X pass -- the conv
// kernel converts X fp32->bf16 inline during its reg-stage (R25 delta).
__global__ void xprep_kernel(const float* __restrict__ P_logit,
                             const float* __restrict__ Q,
                             float* __restrict__ out,
                             unsigned short* __restrict__ Rt) {
  int t = blockIdx.x * blockDim.x + threadIdx.x;
  if (t < SZ_S) out[t] = -INFINITY;            // S init for atomic max

  if (t < K_ * U_) {                           // R / Rt part
    int k = t / U_;
    int u = t - k * U_;
    const float* pl = P_logit + (size_t)k * A_ * U_ + u;
    float v[A_];
    float m = -INFINITY;
#pragma unroll
    for (int a = 0; a < A_; ++a) { v[a] = pl[(size_t)a * U_]; m = fmaxf(m, v[a]); }
    float s = 0.f;
#pragma unroll
    for (int a = 0; a < A_; ++a) { v[a] = expf(v[a] - m); s += v[a]; }
    float qs = 0.f;
#pragma unroll
    for (int a = 0; a < A_; ++a) qs += Q[a];
    float eps = qs * (1.0f / A_);
    float invs = 1.f / s;
    float* Rout = out + SZ_S;
    const int um = (u >> 1) & 3;               // swizzle mask for this u-row
#pragma unroll
    for (int a = 0; a < XPR; ++a) {
      unsigned short bv = 0;
      if (a < A_) {
        float r = logf(fmaxf(v[a] * invs / Q[a], eps));
        Rout[(size_t)(k * A_ + a) * U_ + u] = r;
        bv = f2bf(r);
      }
      int sl = k * XPR + a;
      int w = sl & 31;                         // slot within 32-slot step row
      int widx = (((w >> 3) ^ um) << 3) | (w & 7);   // swizzled position
      Rt[(size_t)(sl >> 5) * (U_ * 32) + u * 32 + widx] = bv;
    }
  }
}

// Conv as one GEMM: M=u (A=R slots), N=l (B=packed-X window), K=480 (15 steps).
// R25 = R23 (best, 120.0 µs) with ONE delta: the separate X-conversion pass is
// FOLDED into conv's T14 reg-stage. Each lane's 16-B LDS chunk (group g =
// c*64+lane) corresponds to packed row g/3, cols (g%3)*8..+7 -> an 8-float
// contiguous fp32 read (2x dwordx4, 4-B aligned; CDNA supports unaligned) +
// 8x f2bf pack at the tile boundary. Pad cols 21..23 are garbage but their R
// slots are ZERO; X rows >= 1024 feed only discarded l >= 1005; one address
// clamp guards the n=383 buffer end. Loads/tile 7->14 (outstanding 14+32=46
// < 63; vmcnt(32) still retires exactly the X loads). Everything else
// identical: persistent swizzled R (120 KB, staged once/block), wave-private
// X buffers, double accumulators, paced stores {1,2,4,5,7,9,10,12}, zero
// barriers after prologue. 4 waves (2u x 2l), wave 64u x 128l.
__global__ __launch_bounds__(256, 1) void conv_kernel(
    const float* __restrict__ Xf,
    const unsigned short* __restrict__ Rt,
    float* __restrict__ out) {
  __shared__ __align__(16) unsigned short lds_r[NSTEP * 4096];     // 120 KB
  __shared__ __align__(16) unsigned short lds_xp[4][XWCH * 512];   // 28 KB

  const int n  = blockIdx.z;
  const int u0 = blockIdx.x * 128;
  const int wid  = threadIdx.x >> 6;
  const int lane = threadIdx.x & 63;
  const int wl = wid >> 1;             // wave l position (0..1), 128 l each
  const int wu = wid & 1;              // wave u position (0..1), 64 u each

  const char* rsrc = (const char*)Rt + (size_t)u0 * 64;   // block's u-half
  char* xdst = (char*)&lds_xp[wid][0];

  const int fl = lane & 15;            // frag row (A: u) / col (B: l)
  const int fj = lane >> 4;            // k sub-chunk (8 shorts each)
  // R read offset with the baked-in swizzle (R23): fj ^ ((fl>>1)&3).
  const int rfo = (wu * 64 + fl) * 32 + ((fj ^ ((fl >> 1) & 3)) << 3);
  const unsigned short* xb =
      (const unsigned short*)xdst + fl * XPR + (fj << 3);
  const int ug = fj << 2;

  float* Z = out + SZ_S + SZ_R;
  float pmax[4][4];                    // [ut][reg], carried across all tiles
#pragma unroll
  for (int ut = 0; ut < 4; ++ut)
#pragma unroll
    for (int r = 0; r < 4; ++r) pmax[ut][r] = -INFINITY;

  f32x4 accA[4][8], accB[4][8];        // double accumulators (256 VGPR)
  uint4v xr[2 * XWCH];                 // X fp32 reg-stage (56 VGPR)

  // paced store-group schedule: group g at step sgk[g]
#define SGK(k) ((k)==1?0:(k)==2?1:(k)==4?2:(k)==5?3:(k)==7?4:(k)==9?5:   \
                (k)==10?6:(k)==12?7:-1)

#define ZERO(ACC)                                                            \
  {                                                                          \
    _Pragma("unroll")                                                        \
    for (int ut = 0; ut < 4; ++ut)                                           \
      _Pragma("unroll")                                                      \
      for (int lt = 0; lt < 8; ++lt)                                         \
        (ACC)[ut][lt] = (f32x4){0.f, 0.f, 0.f, 0.f};                         \
  }

#define KSTEP(K, ACC)                                                        \
  {                                                                          \
    short8 xfr[8], rfr[4];                                                   \
    const unsigned short* rb = lds_r + (K) * 4096 + rfo;                     \
    _Pragma("unroll")                                                        \
    for (int lt = 0; lt < 8; ++lt)                                           \
      xfr[lt] = *(const short8*)(xb + lt * (16 * XPR) + (K) * 32);           \
    _Pragma("unroll")                                                        \
    for (int ut = 0; ut < 4; ++ut)                                           \
      rfr[ut] = *(const short8*)(rb + ut * (16 * 32));                       \
    _Pragma("unroll")                                                        \
    for (int ut = 0; ut < 4; ++ut)                                           \
      _Pragma("unroll")                                                      \
      for (int lt = 0; lt < 8; ++lt)                                         \
        (ACC)[ut][lt] = __builtin_amdgcn_mfma_f32_16x16x32_bf16(             \
            rfr[ut], xfr[lt], (ACC)[ut][lt], 0, 0, 0);                       \
  }

  // store lt-group LT of tile TT from ACC (tiles 0..2: always in-bounds)
#define STORE4(ACC, TT, LT)                                                  \
  {                                                                          \
    const int l = (TT) * 256 + wl * 128 + (LT) * 16 + fl;                    \
    float* zrow = Z + ((size_t)n * LOUT + l) * U_ + u0 + wu * 64 + ug;       \
    _Pragma("unroll")                                                        \
    for (int ut = 0; ut < 4; ++ut) {                                         \
      f32x4 v = (ACC)[ut][LT];                                               \
      *(f32x4*)(zrow + ut * 16) = v;                                         \
      _Pragma("unroll")                                                      \
      for (int r = 0; r < 4; ++r) pmax[ut][r] = fmaxf(pmax[ut][r], v[r]);    \
    }                                                                        \
  }

  // issue X fp32 loads for tile T1: group g = c*64+lane -> row g/3, part g%3;
  // 8 contiguous floats at (base_row + row)*21 + part*8 (clamped).
#define XLOADS(T1)                                                           \
  {                                                                          \
    const size_t base_row = (size_t)n * L_ + (T1) * 256 + wl * 128;          \
    _Pragma("unroll")                                                        \
    for (int c = 0; c < XWCH; ++c) {                                         \
      int idx = c * 64 + lane;                                               \
      int row = idx / 3, part = idx - row * 3;                               \
      size_t f = (base_row + row) * A_ + part * 8;                           \
      if (f > XF_MAX) f = XF_MAX;                                            \
      xr[2 * c]     = *(const uint4v*)(Xf + f);                              \
      xr[2 * c + 1] = *(const uint4v*)(Xf + f + 4);                          \
    }                                                                        \
  }

  // convert staged fp32 -> packed bf16 and write the private LDS buffer
#define XWRITE()                                                             \
  {                                                                          \
    _Pragma("unroll")                                                        \
    for (int c = 0; c < XWCH; ++c) {                                         \
      uint4v o;                                                              \
      _Pragma("unroll")                                                      \
      for (int j = 0; j < 2; ++j) {                                          \
        o[j]     = (unsigned int)f2bf(__uint_as_float(xr[2*c][2*j]))         \
                 | ((unsigned int)f2bf(__uint_as_float(xr[2*c][2*j+1])) << 16);\
        o[j + 2] = (unsigned int)f2bf(__uint_as_float(xr[2*c+1][2*j]))       \
                 | ((unsigned int)f2bf(__uint_as_float(xr[2*c+1][2*j+1])) << 16);\
      }                                                                      \
      *(uint4v*)(xdst + c * 1024 + lane * 16) = o;                           \
    }                                                                        \
  }

  // ---- prologue: ALL of R (30 chunks/wave, shared) + private X tile 0
  for (int c = wid; c < NSTEP * 8; c += 4)
    gload_lds16(rsrc + (size_t)(c >> 3) * (U_ * 64) + (c & 7) * 1024 + lane * 16,
                (char*)lds_r + c * 1024);
  XLOADS(0)
  asm volatile("s_waitcnt vmcnt(0)" ::: "memory");
  XWRITE()
  __builtin_amdgcn_s_barrier();        // the ONLY barrier: lds_r visibility

  // ---- tile 0: compute accA; reg-load X1 (issued before any stores)
  ZERO(accA)
  XLOADS(1)
#pragma unroll
  for (int k = 0; k < NSTEP; ++k) KSTEP(k, accA)
  asm volatile("s_waitcnt vmcnt(0)" ::: "memory");   // xr ready (only loads)
  XWRITE()

  // ---- tile 1: compute accB; paced stores of tile 0; reg-load X2
  ZERO(accB)
  XLOADS(2)
#pragma unroll
  for (int k = 0; k < NSTEP; ++k) {
    KSTEP(k, accB)
    if (SGK(k) >= 0) STORE4(accA, 0, SGK(k))
  }
  asm volatile("s_waitcnt vmcnt(32)" ::: "memory");  // retire 14 oldest = xloads
  XWRITE()

  // ---- tile 2: compute accA; paced stores of tile 1; reg-load X3
  ZERO(accA)
  XLOADS(3)
#pragma unroll
  for (int k = 0; k < NSTEP; ++k) {
    KSTEP(k, accA)
    if (SGK(k) >= 0) STORE4(accB, 1, SGK(k))
  }
  asm volatile("s_waitcnt vmcnt(32)" ::: "memory");
  XWRITE()

  // ---- tile 3: compute accB; paced stores of tile 2
  ZERO(accB)
#pragma unroll
  for (int k = 0; k < NSTEP; ++k) {
    KSTEP(k, accB)
    if (SGK(k) >= 0) STORE4(accA, 2, SGK(k))
  }

  // ---- tail: store tile 3 (guarded: rows 768..1023 vs LOUT=1005)
#pragma unroll
  for (int lt = 0; lt < 8; ++lt) {
    const int l = 768 + wl * 128 + lt * 16 + fl;
    if (l < LOUT) {
      float* zrow = Z + ((size_t)n * LOUT + l) * U_ + u0 + wu * 64 + ug;
#pragma unroll
      for (int ut = 0; ut < 4; ++ut) {
        f32x4 v = accB[ut][lt];
        *(f32x4*)(zrow + ut * 16) = v;
#pragma unroll
        for (int r = 0; r < 4; ++r) pmax[ut][r] = fmaxf(pmax[ut][r], v[r]);
      }
    }
  }

#undef SGK
#undef ZERO
#undef KSTEP
#undef STORE4
#undef XLOADS
#undef XWRITE

  // ---- S epilogue: reduce over the frag's 16 cols (fl), atomics once.
#pragma unroll
  for (int off = 1; off < 16; off <<= 1)
#pragma unroll
    for (int ut = 0; ut < 4; ++ut)
#pragma unroll
      for (int r = 0; r < 4; ++r)
        pmax[ut][r] = fmaxf(pmax[ut][r], __shfl_xor(pmax[ut][r], off));

  if (fl == 0) {                       // lanes fj*16
    const int tn = n / F_;
    float* Sp = out + (size_t)tn * U_ + u0 + wu * 64 + ug;
#pragma unroll
    for (int ut = 0; ut < 4; ++ut)
#pragma unroll
      for (int r = 0; r < 4; ++r)
        atomicMaxF(Sp + ut * 16 + r, pmax[ut][r]);
  }
}

extern "C" void kernel_launch(void* const* d_in, const int* in_sizes, int n_in,
                              void* d_out, int out_size, void* d_ws, size_t ws_size,
                              hipStream_t stream) {
  const float* X       = (const float*)d_in[0];
  const float* P_logit = (const float*)d_in[1];
  const float* Q       = (const float*)d_in[2];
  float* out = (float*)d_out;

  unsigned short* Rt = (unsigned short*)d_ws;            // 240 KB

  hipLaunchKernelGGL(xprep_kernel, dim3(64), dim3(256), 0, stream,
                     P_logit, Q, out, Rt);
  dim3 grid(2, 1, NIMG);   // u-tiles, -, images (4 l-tiles looped in-kernel)
  hipLaunchKernelGGL(conv_kernel, grid, dim3(256), 0, stream, X, Rt, out);
}